// Round 8
// baseline (551.312 us; speedup 1.0000x reference)
//
#include <hip/hip_runtime.h>
#include <hip/hip_fp16.h>
#include <cmath>

typedef __attribute__((ext_vector_type(8))) short short8;
typedef __attribute__((ext_vector_type(8))) unsigned short ushort8;
typedef __attribute__((ext_vector_type(8))) _Float16 f16x8;
typedef __attribute__((ext_vector_type(4))) float f32x4;

__device__ __forceinline__ unsigned pk_bf16(float a, float b) {
  unsigned r;
  asm("v_cvt_pk_bf16_f32 %0, %1, %2" : "=v"(r) : "v"(a), "v"(b));
  return r;  // lo16 = bf16(a), hi16 = bf16(b), RNE
}

__device__ __forceinline__ float fast_tanh(float x) {
  float e2 = __expf(2.0f * x);
  return 1.0f - 2.0f * __builtin_amdgcn_rcpf(e2 + 1.0f);
}

// f32 acc += (f16 lo/hi half of u32) * w  -- single VOP3P instruction
#define FM_LO(A, U, W) \
  asm("v_fma_mix_f32 %0, %1, %2, %0 op_sel_hi:[1,0,0]" : "+v"(A) : "v"(U), "v"(W))
#define FM_HI(A, U, W) \
  asm("v_fma_mix_f32 %0, %1, %2, %0 op_sel:[1,0,0] op_sel_hi:[1,0,0]" : "+v"(A) : "v"(U), "v"(W))

// ---------------- count + wconv (merged, block-partitioned) ----------------

__global__ __launch_bounds__(256) void count_wconv(
    const int* __restrict__ dst, int* __restrict__ cnt, int* __restrict__ epos,
    int E, int nc, const float* __restrict__ W0, const float* __restrict__ W1,
    const float* __restrict__ W2, const float* __restrict__ W3,
    unsigned short* __restrict__ Wt0Hi, unsigned short* __restrict__ Wt0Lo,
    unsigned short* __restrict__ WfHi, unsigned short* __restrict__ WfLo) {
  int b = blockIdx.x;
  if (b < nc) {
    int e = b * 256 + threadIdx.x;
    if (e < E) epos[e] = atomicAdd(&cnt[dst[e]], 1);
    return;
  }
  int t = (b - nc) * 256 + threadIdx.x;  // 0..32767
  int l = t >> 13;
  int idx = t & 8191;
  const float* W = (l == 0) ? W0 : (l == 1) ? W1 : (l == 2) ? W2 : W3;
  int n = idx & 127, k = (idx >> 7) * 2;
  float w0 = W[k * 128 + n], w1 = W[(k + 1) * 128 + n];
  if (l == 0) {
    unsigned h01 = pk_bf16(w0, w1);
    float hf0 = __uint_as_float(h01 << 16);
    float hf1 = __uint_as_float(h01 & 0xFFFF0000u);
    unsigned l01 = pk_bf16(w0 - hf0, w1 - hf1);
    *(unsigned*)&Wt0Hi[n * 128 + k] = h01;
    *(unsigned*)&Wt0Lo[n * 128 + k] = l01;
  } else {
    __half2 hh = __float22half2_rn(make_float2(w0, w1));
    float r0 = __low2float(hh), r1 = __high2float(hh);
    __half2 ll = __float22half2_rn(make_float2((w0 - r0) * 1024.0f,
                                               (w1 - r1) * 1024.0f));
    *(__half2*)&WfHi[(l - 1) * 16384 + n * 128 + k] = hh;
    *(__half2*)&WfLo[(l - 1) * 16384 + n * 128 + k] = ll;
  }
}

// ---------------- single-pass scan (decoupled lookback) ----------------
// also computes dinv/dinv2, rs[N]=E, and per-graph boundaries gstart.

__global__ __launch_bounds__(512) void scan_k(const int* __restrict__ cnt,
                                              int* __restrict__ rs,
                                              unsigned* __restrict__ status,
                                              float* __restrict__ dinv,
                                              float* __restrict__ dinv2,
                                              const int* __restrict__ batch,
                                              int* __restrict__ gstart, int n,
                                              int E, int G) {
  __shared__ int s[512];
  __shared__ int sprev;
  int b = blockIdx.x, tid = threadIdx.x;
  int gid = b * 512 + tid;
  int v = (gid < n) ? cnt[gid] : 0;
  if (gid < n) {
    float deg = 1.0f + (float)v;
    dinv[gid] = rsqrtf(deg);
    dinv2[gid] = __builtin_amdgcn_rcpf(deg);
  }
  s[tid] = v;
  __syncthreads();
  for (int off = 1; off < 512; off <<= 1) {
    int t = (tid >= off) ? s[tid - off] : 0;
    __syncthreads();
    s[tid] += t;
    __syncthreads();
  }
  int incl = s[tid];
  int total = s[511];
  if (tid == 0) {
    if (b == 0) {
      __hip_atomic_store(&status[0], (2u << 30) | (unsigned)total,
                         __ATOMIC_RELAXED, __HIP_MEMORY_SCOPE_AGENT);
      sprev = 0;
    } else {
      __hip_atomic_store(&status[b], (1u << 30) | (unsigned)total,
                         __ATOMIC_RELAXED, __HIP_MEMORY_SCOPE_AGENT);
      int sum = 0;
      int p = b - 1;
      while (true) {
        unsigned st;
        do {
          st = __hip_atomic_load(&status[p], __ATOMIC_RELAXED,
                                 __HIP_MEMORY_SCOPE_AGENT);
        } while ((st >> 30) == 0);
        sum += (int)(st & 0x3FFFFFFFu);
        if ((st >> 30) == 2) break;
        --p;
      }
      __hip_atomic_store(&status[b], (2u << 30) | (unsigned)(sum + total),
                         __ATOMIC_RELAXED, __HIP_MEMORY_SCOPE_AGENT);
      sprev = sum;
    }
  }
  __syncthreads();
  if (gid < n) rs[gid] = sprev + incl - v;
  if (gid == n) rs[n] = E;
  if (b == 0 && tid <= G) {
    int lo = 0, hi = n;
    while (lo < hi) {
      int mid = (lo + hi) >> 1;
      if (batch[mid] < tid) lo = mid + 1;
      else hi = mid;
    }
    gstart[tid] = lo;
  }
}

// ---------------- fill (packed edata, nontemporal scattered store) --------

__global__ __launch_bounds__(256) void fill_k(const int* __restrict__ src,
                                              const int* __restrict__ dst,
                                              const int* __restrict__ rs,
                                              const int* __restrict__ epos,
                                              const float* __restrict__ dinv,
                                              int2* __restrict__ edata, int E) {
  int e = blockIdx.x * 256 + threadIdx.x;
  if (e >= E) return;
  int s = src[e], d = dst[e];
  int pos = rs[d] + epos[e];
  unsigned nw = __float_as_uint(dinv[s] * dinv[d]);
  unsigned long long u = ((unsigned long long)nw << 32) | (unsigned)s;
  __builtin_nontemporal_store(u, (unsigned long long*)&edata[pos]);
}

// ---------------- layer-0 GEMM: f32 A, split-bf16 3-MFMA ----------------

#define LDK 136

__global__ __launch_bounds__(256) void gemm_mfma(const float* __restrict__ A,
                                                 const unsigned short* __restrict__ WtHi,
                                                 const unsigned short* __restrict__ WtLo,
                                                 __half* __restrict__ O, int M) {
  __shared__ unsigned short sHi[128 * LDK];
  __shared__ unsigned short sLo[128 * LDK];
  int tid = threadIdx.x;
#pragma unroll
  for (int i = 0; i < 8; ++i) {
    int c = tid + i * 256;
    int n = c >> 4;
    int off = (c & 15) * 8;
    *(ushort8*)&sHi[n * LDK + off] = *(const ushort8*)&WtHi[c * 8];
    *(ushort8*)&sLo[n * LDK + off] = *(const ushort8*)&WtLo[c * 8];
  }
  __syncthreads();

  int wv = tid >> 6, lane = tid & 63;
  int r0 = blockIdx.x * 128 + wv * 32;
  int lrow = lane & 15, lk = (lane >> 4) * 8;

  f32x4 acc[2][8] = {};
#pragma unroll
  for (int kk = 0; kk < 4; ++kk) {
    int k0 = kk * 32 + lk;
    short8 ahi[2], alo[2];
#pragma unroll
    for (int fr = 0; fr < 2; ++fr) {
      int row = r0 + fr * 16 + lrow;
      row = row < M ? row : M - 1;
      const float* ap = &A[(size_t)row * 128 + k0];
      float4 a0 = *(const float4*)ap;
      float4 a1 = *(const float4*)(ap + 4);
      union { short8 v; unsigned u32[4]; } h_, l_;
#define SPLIT2(slot, x, y)                              \
      {                                                 \
        unsigned hh = pk_bf16((x), (y));                \
        h_.u32[slot] = hh;                              \
        float hf0 = __uint_as_float(hh << 16);          \
        float hf1 = __uint_as_float(hh & 0xFFFF0000u);  \
        l_.u32[slot] = pk_bf16((x) - hf0, (y) - hf1);   \
      }
      SPLIT2(0, a0.x, a0.y)
      SPLIT2(1, a0.z, a0.w)
      SPLIT2(2, a1.x, a1.y)
      SPLIT2(3, a1.z, a1.w)
#undef SPLIT2
      ahi[fr] = h_.v;
      alo[fr] = l_.v;
    }
#pragma unroll
    for (int c = 0; c < 8; ++c) {
      int bidx = (c * 16 + lrow) * LDK + k0;
      short8 bhi = *(const short8*)&sHi[bidx];
      short8 blo = *(const short8*)&sLo[bidx];
#pragma unroll
      for (int fr = 0; fr < 2; ++fr) {
        acc[fr][c] = __builtin_amdgcn_mfma_f32_16x16x32_bf16(ahi[fr], bhi, acc[fr][c], 0, 0, 0);
        acc[fr][c] = __builtin_amdgcn_mfma_f32_16x16x32_bf16(ahi[fr], blo, acc[fr][c], 0, 0, 0);
        acc[fr][c] = __builtin_amdgcn_mfma_f32_16x16x32_bf16(alo[fr], bhi, acc[fr][c], 0, 0, 0);
      }
    }
  }
#pragma unroll
  for (int fr = 0; fr < 2; ++fr) {
#pragma unroll
    for (int c = 0; c < 8; ++c) {
#pragma unroll
      for (int r = 0; r < 4; ++r) {
        int row = r0 + fr * 16 + (lane >> 4) * 4 + r;
        if (row < M)
          O[(size_t)row * 128 + c * 16 + (lane & 15)] = __float2half(acc[fr][c][r]);
      }
    }
  }
}

// ---------------- layers 1-3 GEMM: fp16 A, W = Whi + Wlo*2^-10 ----------------

__global__ __launch_bounds__(256) void gemm_f16(const __half* __restrict__ Hf,
                                                const unsigned short* __restrict__ Whi,
                                                const unsigned short* __restrict__ Wlo,
                                                __half* __restrict__ O, int M) {
  __shared__ unsigned short sHi[128 * LDK];
  __shared__ unsigned short sLo[128 * LDK];
  int tid = threadIdx.x;
#pragma unroll
  for (int i = 0; i < 8; ++i) {
    int c = tid + i * 256;
    int n = c >> 4;
    int off = (c & 15) * 8;
    *(ushort8*)&sHi[n * LDK + off] = *(const ushort8*)&Whi[c * 8];
    *(ushort8*)&sLo[n * LDK + off] = *(const ushort8*)&Wlo[c * 8];
  }
  __syncthreads();

  int wv = tid >> 6, lane = tid & 63;
  int r0 = blockIdx.x * 128 + wv * 32;
  int lrow = lane & 15, lk = (lane >> 4) * 8;

  f32x4 acc[2][8] = {};
  f32x4 accL[2][8] = {};
#pragma unroll
  for (int kk = 0; kk < 4; ++kk) {
    int k0 = kk * 32 + lk;
    f16x8 a[2];
#pragma unroll
    for (int fr = 0; fr < 2; ++fr) {
      int row = r0 + fr * 16 + lrow;
      row = row < M ? row : M - 1;
      a[fr] = *(const f16x8*)&Hf[(size_t)row * 128 + k0];
    }
#pragma unroll
    for (int c = 0; c < 8; ++c) {
      int bidx = (c * 16 + lrow) * LDK + k0;
      f16x8 bhi = *(const f16x8*)&sHi[bidx];
      f16x8 blo = *(const f16x8*)&sLo[bidx];
#pragma unroll
      for (int fr = 0; fr < 2; ++fr) {
        acc[fr][c] = __builtin_amdgcn_mfma_f32_16x16x32_f16(a[fr], bhi, acc[fr][c], 0, 0, 0);
        accL[fr][c] = __builtin_amdgcn_mfma_f32_16x16x32_f16(a[fr], blo, accL[fr][c], 0, 0, 0);
      }
    }
  }
  const float ls = 1.0f / 1024.0f;
#pragma unroll
  for (int fr = 0; fr < 2; ++fr) {
#pragma unroll
    for (int c = 0; c < 8; ++c) {
#pragma unroll
      for (int r = 0; r < 4; ++r) {
        int row = r0 + fr * 16 + (lane >> 4) * 4 + r;
        if (row < M)
          O[(size_t)row * 128 + c * 16 + (lane & 15)] =
              __float2half(acc[fr][c][r] + accL[fr][c][r] * ls);
      }
    }
  }
}

// ---------------- fused gather + self-loop + bias + tanh ----------------
// software-pipelined: next group's edata loads issue alongside current rows.

template <bool FINAL>
__global__ __launch_bounds__(256) void gather_k(const __half* __restrict__ h,
                                                const int* __restrict__ rs,
                                                const int2* __restrict__ edata,
                                                const float* __restrict__ dinv2,
                                                const float* __restrict__ bias,
                                                __half* __restrict__ Hf,
                                                unsigned* __restrict__ OHi,
                                                unsigned* __restrict__ OLo, int N) {
  int wid = (int)((blockIdx.x * (size_t)blockDim.x + threadIdx.x) >> 6);
  if (wid >= N) return;
  int lane = threadIdx.x & 63;
  int grp = lane >> 4;   // 0..3: edge slot
  int li = lane & 15;    // feature chunk: features [li*8, li*8+8)
  int s = rs[wid], e = rs[wid + 1];
  const uint4* hrow = (const uint4*)h;  // row i = hrow[i*16 + li]

  float ac[8] = {};
  int n16 = (e - s) >> 4;
  int base = s + grp;
#define ACC(U, W)                                        \
  {                                                      \
    FM_LO(ac[0], (U).x, (W)); FM_HI(ac[1], (U).x, (W));  \
    FM_LO(ac[2], (U).y, (W)); FM_HI(ac[3], (U).y, (W));  \
    FM_LO(ac[4], (U).z, (W)); FM_HI(ac[5], (U).z, (W));  \
    FM_LO(ac[6], (U).w, (W)); FM_HI(ac[7], (U).w, (W));  \
  }
  if (n16 > 0) {
    int2 e0 = edata[base], e1 = edata[base + 4], e2 = edata[base + 8],
         e3 = edata[base + 12];
    for (int it = 0; it < n16 - 1; ++it) {
      int nb = base + 16;
      uint4 v0 = hrow[(size_t)e0.x * 16 + li];
      uint4 v1 = hrow[(size_t)e1.x * 16 + li];
      uint4 v2 = hrow[(size_t)e2.x * 16 + li];
      uint4 v3 = hrow[(size_t)e3.x * 16 + li];
      int2 f0 = edata[nb], f1 = edata[nb + 4], f2 = edata[nb + 8],
           f3 = edata[nb + 12];
      float w0 = __int_as_float(e0.y), w1 = __int_as_float(e1.y),
            w2 = __int_as_float(e2.y), w3 = __int_as_float(e3.y);
      ACC(v0, w0) ACC(v1, w1) ACC(v2, w2) ACC(v3, w3)
      e0 = f0; e1 = f1; e2 = f2; e3 = f3;
      base = nb;
    }
    uint4 v0 = hrow[(size_t)e0.x * 16 + li];
    uint4 v1 = hrow[(size_t)e1.x * 16 + li];
    uint4 v2 = hrow[(size_t)e2.x * 16 + li];
    uint4 v3 = hrow[(size_t)e3.x * 16 + li];
    float w0 = __int_as_float(e0.y), w1 = __int_as_float(e1.y),
          w2 = __int_as_float(e2.y), w3 = __int_as_float(e3.y);
    ACC(v0, w0) ACC(v1, w1) ACC(v2, w2) ACC(v3, w3)
    base += 16;
  }
  for (int idx = base; idx < e; idx += 4) {
    int2 ed = edata[idx];
    float w = __int_as_float(ed.y);
    uint4 v = hrow[(size_t)ed.x * 16 + li];
    ACC(v, w)
  }
#undef ACC
#pragma unroll
  for (int j = 0; j < 8; ++j) {
    ac[j] += __shfl_xor(ac[j], 16);
    ac[j] += __shfl_xor(ac[j], 32);
  }

  // group g finalizes features {li*8+2g, li*8+2g+1}
  float a0 = grp == 0 ? ac[0] : grp == 1 ? ac[2] : grp == 2 ? ac[4] : ac[6];
  float a1 = grp == 0 ? ac[1] : grp == 1 ? ac[3] : grp == 2 ? ac[5] : ac[7];

  float d2 = dinv2[wid];
  uint4 sv = hrow[(size_t)wid * 16 + li];
  unsigned su = grp == 0 ? sv.x : grp == 1 ? sv.y : grp == 2 ? sv.z : sv.w;
  float2 sj = __half22float2(*(__half2*)&su);
  float2 bj = *(const float2*)&bias[li * 8 + 2 * grp];
  float o0 = fast_tanh(a0 + sj.x * d2 + bj.x);
  float o1 = fast_tanh(a1 + sj.y * d2 + bj.y);

  if (FINAL) {
    unsigned hp = pk_bf16(o0, o1);
    float r0f = __uint_as_float(hp << 16);
    float r1f = __uint_as_float(hp & 0xFFFF0000u);
    unsigned lp = pk_bf16(o0 - r0f, o1 - r1f);
    unsigned oidx = (unsigned)wid * 64 + li * 4 + grp;
    OHi[oidx] = hp;
    OLo[oidx] = lp;
  } else {
    __half2 hv = __float22half2_rn(make_float2(o0, o1));
    *(__half2*)&Hf[(size_t)wid * 128 + li * 8 + 2 * grp] = hv;
  }
}

// ---------------- pooling ----------------

#define CH 16

__global__ __launch_bounds__(128) void pool_partial(const unsigned short* __restrict__ Hi,
                                                    const unsigned short* __restrict__ Lo,
                                                    const int* __restrict__ gstart,
                                                    float* __restrict__ pmax,
                                                    float* __restrict__ psum) {
  int g = blockIdx.x, c = blockIdx.y, f = threadIdx.x;
  int s = gstart[g], e = gstart[g + 1];
  long long len = e - s;
  int cs = s + (int)(len * c / CH);
  int ce = s + (int)(len * (c + 1) / CH);
  float m = -INFINITY, sum = 0.f;
  for (int n = cs; n < ce; ++n) {
    unsigned hv = Hi[(size_t)n * 128 + f];
    unsigned lv = Lo[(size_t)n * 128 + f];
    float v = __uint_as_float(hv << 16) + __uint_as_float(lv << 16);
    m = fmaxf(m, v);
    sum += v;
  }
  pmax[((size_t)g * CH + c) * 128 + f] = m;
  psum[((size_t)g * CH + c) * 128 + f] = sum;
}

__global__ __launch_bounds__(128) void pool_head(const float* __restrict__ pmax,
                                                 const float* __restrict__ psum,
                                                 const int* __restrict__ gstart,
                                                 const float* __restrict__ Wout,
                                                 const float* __restrict__ bout,
                                                 float* __restrict__ out, int G) {
  __shared__ float pl[256];
  int g = blockIdx.x, f = threadIdx.x;
  float m = -INFINITY, s = 0.f;
  for (int c = 0; c < CH; ++c) {
    m = fmaxf(m, pmax[((size_t)g * CH + c) * 128 + f]);
    s += psum[((size_t)g * CH + c) * 128 + f];
  }
  int cnt = gstart[g + 1] - gstart[g];
  float mean = s / fmaxf((float)cnt, 1.0f);
  float* pooled = out + (size_t)G * 10;
  pooled[(size_t)g * 256 + f] = m;
  pooled[(size_t)g * 256 + 128 + f] = mean;
  pl[f] = m;
  pl[128 + f] = mean;
  __syncthreads();
  if (f < 10) {
    float acc = bout[f];
    for (int k = 0; k < 256; ++k) acc += pl[k] * Wout[k * 10 + f];
    out[(size_t)g * 10 + f] = acc;
  }
}

// ---------------- launch ----------------

extern "C" void kernel_launch(void* const* d_in, const int* in_sizes, int n_in,
                              void* d_out, int out_size, void* d_ws, size_t ws_size,
                              hipStream_t stream) {
  const float* x = (const float*)d_in[0];
  const int* ei = (const int*)d_in[1];
  const int* batch = (const int*)d_in[2];
  const float* W[4] = {(const float*)d_in[3], (const float*)d_in[5],
                       (const float*)d_in[7], (const float*)d_in[9]};
  const float* Bz[4] = {(const float*)d_in[4], (const float*)d_in[6],
                        (const float*)d_in[8], (const float*)d_in[10]};
  const float* Wout = (const float*)d_in[11];
  const float* bout = (const float*)d_in[12];
  const int N = in_sizes[0] / 128;
  const int E = in_sizes[1] / 2;
  const int G = 64;
  const int* srcp = ei;
  const int* dstp = ei + E;
  float* out = (float*)d_out;

  char* wsb = (char*)d_ws;
  size_t off = 0;
  auto alloc = [&](size_t bytes) -> void* {
    void* p = wsb + off;
    off = (off + bytes + 255) & ~(size_t)255;
    return p;
  };
  __half* bufA = (__half*)alloc((size_t)N * 128 * 2);    // GEMM out (fp16)
  __half* Hf = (__half*)alloc((size_t)N * 128 * 2);      // gather out (fp16)
  unsigned* OHi = (unsigned*)alloc((size_t)N * 64 * 4);  // final bf16-hi pairs
  unsigned* OLo = (unsigned*)alloc((size_t)N * 64 * 4);  // final bf16-lo pairs
  size_t cnt_off = off;
  int* cnt = (int*)alloc((size_t)N * 4);
  int nsb = (N + 511) / 512;
  unsigned* status = (unsigned*)alloc((size_t)nsb * 4);
  size_t cnt_span = off - cnt_off;  // cnt + status, zeroed together
  int* epos = (int*)alloc((size_t)E * 4);
  float* dinv = (float*)alloc((size_t)N * 4);
  float* dinv2 = (float*)alloc((size_t)N * 4);
  int* rs = (int*)alloc((size_t)(N + 1) * 4);
  int2* edata = (int2*)alloc((size_t)E * 8);
  int* gstart = (int*)alloc(4096);
  float* pmax = (float*)alloc((size_t)G * CH * 128 * 4);
  float* psum = (float*)alloc((size_t)G * CH * 128 * 4);
  unsigned short* Wt0Hi = (unsigned short*)alloc(16384 * 2);
  unsigned short* Wt0Lo = (unsigned short*)alloc(16384 * 2);
  unsigned short* WfHi = (unsigned short*)alloc(3 * 16384 * 2);
  unsigned short* WfLo = (unsigned short*)alloc(3 * 16384 * 2);
  if (off > ws_size) return;

  hipMemsetAsync(wsb + cnt_off, 0, cnt_span, stream);

  int nc = (E + 255) / 256;
  count_wconv<<<nc + 128, 256, 0, stream>>>(dstp, cnt, epos, E, nc, W[0], W[1],
                                            W[2], W[3], Wt0Hi, Wt0Lo, WfHi, WfLo);
  scan_k<<<nsb, 512, 0, stream>>>(cnt, rs, status, dinv, dinv2, batch, gstart, N,
                                  E, G);
  fill_k<<<(E + 255) / 256, 256, 0, stream>>>(srcp, dstp, rs, epos, dinv, edata, E);

  int ggrid = (int)(((size_t)N * 64 + 255) / 256);
  for (int l = 0; l < 4; ++l) {
    if (l == 0)
      gemm_mfma<<<(N + 127) / 128, 256, 0, stream>>>(x, Wt0Hi, Wt0Lo, bufA, N);
    else
      gemm_f16<<<(N + 127) / 128, 256, 0, stream>>>(Hf, WfHi + (l - 1) * 16384,
                                                    WfLo + (l - 1) * 16384, bufA, N);
    if (l < 3)
      gather_k<false><<<ggrid, 256, 0, stream>>>(bufA, rs, edata, dinv2, Bz[l], Hf,
                                                 OHi, OLo, N);
    else
      gather_k<true><<<ggrid, 256, 0, stream>>>(bufA, rs, edata, dinv2, Bz[l], Hf,
                                                OHi, OLo, N);
  }

  pool_partial<<<dim3(G, CH), 128, 0, stream>>>((const unsigned short*)OHi,
                                                (const unsigned short*)OLo, gstart,
                                                pmax, psum);
  pool_head<<<G, 128, 0, stream>>>(pmax, psum, gstart, Wout, bout, out, G);
}

// Round 10
// 516.272 us; speedup vs baseline: 1.0679x; 1.0679x over previous
//
#include <hip/hip_runtime.h>
#include <hip/hip_fp16.h>
#include <cmath>

typedef __attribute__((ext_vector_type(8))) short short8;
typedef __attribute__((ext_vector_type(8))) unsigned short ushort8;
typedef __attribute__((ext_vector_type(8))) _Float16 f16x8;
typedef __attribute__((ext_vector_type(4))) float f32x4;

__device__ __forceinline__ unsigned pk_bf16(float a, float b) {
  unsigned r;
  asm("v_cvt_pk_bf16_f32 %0, %1, %2" : "=v"(r) : "v"(a), "v"(b));
  return r;  // lo16 = bf16(a), hi16 = bf16(b), RNE
}

__device__ __forceinline__ float fast_tanh(float x) {
  float e2 = __expf(2.0f * x);
  return 1.0f - 2.0f * __builtin_amdgcn_rcpf(e2 + 1.0f);
}

// f32 acc += (f16 lo/hi half of u32) * w  -- single VOP3P instruction
#define FM_LO(A, U, W) \
  asm("v_fma_mix_f32 %0, %1, %2, %0 op_sel_hi:[1,0,0]" : "+v"(A) : "v"(U), "v"(W))
#define FM_HI(A, U, W) \
  asm("v_fma_mix_f32 %0, %1, %2, %0 op_sel:[1,0,0] op_sel_hi:[1,0,0]" : "+v"(A) : "v"(U), "v"(W))

// ---------------- count + wconv (merged, block-partitioned) ----------------

__global__ __launch_bounds__(256) void count_wconv(
    const int* __restrict__ dst, int* __restrict__ cnt, int* __restrict__ epos,
    int E, int nc, const float* __restrict__ W0, const float* __restrict__ W1,
    const float* __restrict__ W2, const float* __restrict__ W3,
    unsigned short* __restrict__ Wt0Hi, unsigned short* __restrict__ Wt0Lo,
    unsigned short* __restrict__ WfHi, unsigned short* __restrict__ WfLo) {
  int b = blockIdx.x;
  if (b < nc) {
    int e = b * 256 + threadIdx.x;
    if (e < E) epos[e] = atomicAdd(&cnt[dst[e]], 1);
    return;
  }
  int t = (b - nc) * 256 + threadIdx.x;  // 0..32767
  int l = t >> 13;
  int idx = t & 8191;
  const float* W = (l == 0) ? W0 : (l == 1) ? W1 : (l == 2) ? W2 : W3;
  int n = idx & 127, k = (idx >> 7) * 2;
  float w0 = W[k * 128 + n], w1 = W[(k + 1) * 128 + n];
  if (l == 0) {
    unsigned h01 = pk_bf16(w0, w1);
    float hf0 = __uint_as_float(h01 << 16);
    float hf1 = __uint_as_float(h01 & 0xFFFF0000u);
    unsigned l01 = pk_bf16(w0 - hf0, w1 - hf1);
    *(unsigned*)&Wt0Hi[n * 128 + k] = h01;
    *(unsigned*)&Wt0Lo[n * 128 + k] = l01;
  } else {
    __half2 hh = __float22half2_rn(make_float2(w0, w1));
    float r0 = __low2float(hh), r1 = __high2float(hh);
    __half2 ll = __float22half2_rn(make_float2((w0 - r0) * 1024.0f,
                                               (w1 - r1) * 1024.0f));
    *(__half2*)&WfHi[(l - 1) * 16384 + n * 128 + k] = hh;
    *(__half2*)&WfLo[(l - 1) * 16384 + n * 128 + k] = ll;
  }
}

// ---------------- 3-phase scan (R7 proven) ----------------

__global__ __launch_bounds__(512) void scan_a(const int* __restrict__ cnt,
                                              int* __restrict__ rs,
                                              int* __restrict__ bsum,
                                              float* __restrict__ dinv,
                                              float* __restrict__ dinv2, int n) {
  __shared__ int s[512];
  int tid = threadIdx.x;
  int gid = blockIdx.x * 512 + tid;
  int v = (gid < n) ? cnt[gid] : 0;
  if (gid < n) {
    float deg = 1.0f + (float)v;
    dinv[gid] = rsqrtf(deg);
    dinv2[gid] = __builtin_amdgcn_rcpf(deg);
  }
  s[tid] = v;
  __syncthreads();
  for (int off = 1; off < 512; off <<= 1) {
    int t = (tid >= off) ? s[tid - off] : 0;
    __syncthreads();
    s[tid] += t;
    __syncthreads();
  }
  if (gid < n) rs[gid] = s[tid] - v;
  if (tid == 511) bsum[blockIdx.x] = s[511];
}

__global__ __launch_bounds__(256) void scan_b(const int* __restrict__ bsum,
                                              int* __restrict__ boff, int nb,
                                              const int* __restrict__ batch,
                                              int* __restrict__ gstart, int n,
                                              int G) {
  __shared__ int s[256];
  int tid = threadIdx.x;
  int v = (tid < nb) ? bsum[tid] : 0;
  s[tid] = v;
  __syncthreads();
  for (int off = 1; off < 256; off <<= 1) {
    int t = (tid >= off) ? s[tid - off] : 0;
    __syncthreads();
    s[tid] += t;
    __syncthreads();
  }
  if (tid < nb) boff[tid] = s[tid] - v;
  if (tid <= G) {
    int lo = 0, hi = n;
    while (lo < hi) {
      int mid = (lo + hi) >> 1;
      if (batch[mid] < tid) lo = mid + 1;
      else hi = mid;
    }
    gstart[tid] = lo;
  }
}

__global__ __launch_bounds__(512) void scan_c(const int* __restrict__ boff,
                                              int* __restrict__ rs, int n, int E) {
  int gid = blockIdx.x * 512 + threadIdx.x;
  if (gid < n) rs[gid] += boff[blockIdx.x];
  if (gid == 0) rs[n] = E;
}

// ---------------- fill (packed edata, plain store) ----------------

__global__ __launch_bounds__(256) void fill_k(const int* __restrict__ src,
                                              const int* __restrict__ dst,
                                              const int* __restrict__ rs,
                                              const int* __restrict__ epos,
                                              const float* __restrict__ dinv,
                                              int2* __restrict__ edata, int E) {
  int e = blockIdx.x * 256 + threadIdx.x;
  if (e >= E) return;
  int s = src[e], d = dst[e];
  int pos = rs[d] + epos[e];
  int2 ed;
  ed.x = s;
  ed.y = __float_as_int(dinv[s] * dinv[d]);
  edata[pos] = ed;
}

// ---------------- layer-0 GEMM: f32 A, split-bf16 3-MFMA ----------------

#define LDK 136

__global__ __launch_bounds__(256) void gemm_mfma(const float* __restrict__ A,
                                                 const unsigned short* __restrict__ WtHi,
                                                 const unsigned short* __restrict__ WtLo,
                                                 __half* __restrict__ O, int M) {
  __shared__ unsigned short sHi[128 * LDK];
  __shared__ unsigned short sLo[128 * LDK];
  int tid = threadIdx.x;
#pragma unroll
  for (int i = 0; i < 8; ++i) {
    int c = tid + i * 256;
    int n = c >> 4;
    int off = (c & 15) * 8;
    *(ushort8*)&sHi[n * LDK + off] = *(const ushort8*)&WtHi[c * 8];
    *(ushort8*)&sLo[n * LDK + off] = *(const ushort8*)&WtLo[c * 8];
  }
  __syncthreads();

  int wv = tid >> 6, lane = tid & 63;
  int r0 = blockIdx.x * 128 + wv * 32;
  int lrow = lane & 15, lk = (lane >> 4) * 8;

  f32x4 acc[2][8] = {};
#pragma unroll
  for (int kk = 0; kk < 4; ++kk) {
    int k0 = kk * 32 + lk;
    short8 ahi[2], alo[2];
#pragma unroll
    for (int fr = 0; fr < 2; ++fr) {
      int row = r0 + fr * 16 + lrow;
      row = row < M ? row : M - 1;
      const float* ap = &A[(size_t)row * 128 + k0];
      float4 a0 = *(const float4*)ap;
      float4 a1 = *(const float4*)(ap + 4);
      union { short8 v; unsigned u32[4]; } h_, l_;
#define SPLIT2(slot, x, y)                              \
      {                                                 \
        unsigned hh = pk_bf16((x), (y));                \
        h_.u32[slot] = hh;                              \
        float hf0 = __uint_as_float(hh << 16);          \
        float hf1 = __uint_as_float(hh & 0xFFFF0000u);  \
        l_.u32[slot] = pk_bf16((x) - hf0, (y) - hf1);   \
      }
      SPLIT2(0, a0.x, a0.y)
      SPLIT2(1, a0.z, a0.w)
      SPLIT2(2, a1.x, a1.y)
      SPLIT2(3, a1.z, a1.w)
#undef SPLIT2
      ahi[fr] = h_.v;
      alo[fr] = l_.v;
    }
#pragma unroll
    for (int c = 0; c < 8; ++c) {
      int bidx = (c * 16 + lrow) * LDK + k0;
      short8 bhi = *(const short8*)&sHi[bidx];
      short8 blo = *(const short8*)&sLo[bidx];
#pragma unroll
      for (int fr = 0; fr < 2; ++fr) {
        acc[fr][c] = __builtin_amdgcn_mfma_f32_16x16x32_bf16(ahi[fr], bhi, acc[fr][c], 0, 0, 0);
        acc[fr][c] = __builtin_amdgcn_mfma_f32_16x16x32_bf16(ahi[fr], blo, acc[fr][c], 0, 0, 0);
        acc[fr][c] = __builtin_amdgcn_mfma_f32_16x16x32_bf16(alo[fr], bhi, acc[fr][c], 0, 0, 0);
      }
    }
  }
#pragma unroll
  for (int fr = 0; fr < 2; ++fr) {
#pragma unroll
    for (int c = 0; c < 8; ++c) {
#pragma unroll
      for (int r = 0; r < 4; ++r) {
        int row = r0 + fr * 16 + (lane >> 4) * 4 + r;
        if (row < M)
          O[(size_t)row * 128 + c * 16 + (lane & 15)] = __float2half(acc[fr][c][r]);
      }
    }
  }
}

// ---------------- layers 1-3 GEMM: fp16 A, W = Whi + Wlo*2^-10 ----------------

__global__ __launch_bounds__(256) void gemm_f16(const __half* __restrict__ Hf,
                                                const unsigned short* __restrict__ Whi,
                                                const unsigned short* __restrict__ Wlo,
                                                __half* __restrict__ O, int M) {
  __shared__ unsigned short sHi[128 * LDK];
  __shared__ unsigned short sLo[128 * LDK];
  int tid = threadIdx.x;
#pragma unroll
  for (int i = 0; i < 8; ++i) {
    int c = tid + i * 256;
    int n = c >> 4;
    int off = (c & 15) * 8;
    *(ushort8*)&sHi[n * LDK + off] = *(const ushort8*)&Whi[c * 8];
    *(ushort8*)&sLo[n * LDK + off] = *(const ushort8*)&Wlo[c * 8];
  }
  __syncthreads();

  int wv = tid >> 6, lane = tid & 63;
  int r0 = blockIdx.x * 128 + wv * 32;
  int lrow = lane & 15, lk = (lane >> 4) * 8;

  f32x4 acc[2][8] = {};
  f32x4 accL[2][8] = {};
#pragma unroll
  for (int kk = 0; kk < 4; ++kk) {
    int k0 = kk * 32 + lk;
    f16x8 a[2];
#pragma unroll
    for (int fr = 0; fr < 2; ++fr) {
      int row = r0 + fr * 16 + lrow;
      row = row < M ? row : M - 1;
      a[fr] = *(const f16x8*)&Hf[(size_t)row * 128 + k0];
    }
#pragma unroll
    for (int c = 0; c < 8; ++c) {
      int bidx = (c * 16 + lrow) * LDK + k0;
      f16x8 bhi = *(const f16x8*)&sHi[bidx];
      f16x8 blo = *(const f16x8*)&sLo[bidx];
#pragma unroll
      for (int fr = 0; fr < 2; ++fr) {
        acc[fr][c] = __builtin_amdgcn_mfma_f32_16x16x32_f16(a[fr], bhi, acc[fr][c], 0, 0, 0);
        accL[fr][c] = __builtin_amdgcn_mfma_f32_16x16x32_f16(a[fr], blo, accL[fr][c], 0, 0, 0);
      }
    }
  }
  const float ls = 1.0f / 1024.0f;
#pragma unroll
  for (int fr = 0; fr < 2; ++fr) {
#pragma unroll
    for (int c = 0; c < 8; ++c) {
#pragma unroll
      for (int r = 0; r < 4; ++r) {
        int row = r0 + fr * 16 + (lane >> 4) * 4 + r;
        if (row < M)
          O[(size_t)row * 128 + c * 16 + (lane & 15)] =
              __float2half(acc[fr][c][r] + accL[fr][c][r] * ls);
      }
    }
  }
}

// ---------------- fused gather + self-loop + bias + tanh ----------------
// always-full-width 16-edge loop with clamped indices + zero pad weights;
// nontemporal edata loads (u64 scalar form), h rows stay in L2.

__global__ __launch_bounds__(256) void gather_k(const __half* __restrict__ h,
                                                const int* __restrict__ rs,
                                                const int2* __restrict__ edata,
                                                const float* __restrict__ dinv2,
                                                const float* __restrict__ bias,
                                                __half* __restrict__ Hf, int N) {
  int wid = (int)((blockIdx.x * (size_t)blockDim.x + threadIdx.x) >> 6);
  if (wid >= N) return;
  int lane = threadIdx.x & 63;
  int grp = lane >> 4;   // 0..3: edge slot
  int li = lane & 15;    // feature chunk: features [li*8, li*8+8)
  int s = rs[wid], e = rs[wid + 1];
  const uint4* hrow = (const uint4*)h;  // row i = hrow[i*16 + li]
  const unsigned long long* ed64 = (const unsigned long long*)edata;

  float ac[8] = {};
  int niter = (e - s + 15) >> 4;
  int base = s + grp;
#define ACC(U, W)                                        \
  {                                                      \
    FM_LO(ac[0], (U).x, (W)); FM_HI(ac[1], (U).x, (W));  \
    FM_LO(ac[2], (U).y, (W)); FM_HI(ac[3], (U).y, (W));  \
    FM_LO(ac[4], (U).z, (W)); FM_HI(ac[5], (U).z, (W));  \
    FM_LO(ac[6], (U).w, (W)); FM_HI(ac[7], (U).w, (W));  \
  }
  for (int it = 0; it < niter; ++it, base += 16) {
    int p0 = base, p1 = base + 4, p2 = base + 8, p3 = base + 12;
    int c0 = p0 < e ? p0 : s, c1 = p1 < e ? p1 : s;
    int c2 = p2 < e ? p2 : s, c3 = p3 < e ? p3 : s;
    unsigned long long u0 = __builtin_nontemporal_load(&ed64[c0]);
    unsigned long long u1 = __builtin_nontemporal_load(&ed64[c1]);
    unsigned long long u2 = __builtin_nontemporal_load(&ed64[c2]);
    unsigned long long u3 = __builtin_nontemporal_load(&ed64[c3]);
    unsigned i0 = (unsigned)u0, i1 = (unsigned)u1;
    unsigned i2 = (unsigned)u2, i3 = (unsigned)u3;
    float w0 = p0 < e ? __uint_as_float((unsigned)(u0 >> 32)) : 0.0f;
    float w1 = p1 < e ? __uint_as_float((unsigned)(u1 >> 32)) : 0.0f;
    float w2 = p2 < e ? __uint_as_float((unsigned)(u2 >> 32)) : 0.0f;
    float w3 = p3 < e ? __uint_as_float((unsigned)(u3 >> 32)) : 0.0f;
    uint4 v0 = hrow[(size_t)i0 * 16 + li];
    uint4 v1 = hrow[(size_t)i1 * 16 + li];
    uint4 v2 = hrow[(size_t)i2 * 16 + li];
    uint4 v3 = hrow[(size_t)i3 * 16 + li];
    ACC(v0, w0) ACC(v1, w1) ACC(v2, w2) ACC(v3, w3)
  }
#undef ACC
#pragma unroll
  for (int j = 0; j < 8; ++j) {
    ac[j] += __shfl_xor(ac[j], 16);
    ac[j] += __shfl_xor(ac[j], 32);
  }

  // group g finalizes features {li*8+2g, li*8+2g+1}
  float a0 = grp == 0 ? ac[0] : grp == 1 ? ac[2] : grp == 2 ? ac[4] : ac[6];
  float a1 = grp == 0 ? ac[1] : grp == 1 ? ac[3] : grp == 2 ? ac[5] : ac[7];

  float d2 = dinv2[wid];
  uint4 sv = hrow[(size_t)wid * 16 + li];
  unsigned su = grp == 0 ? sv.x : grp == 1 ? sv.y : grp == 2 ? sv.z : sv.w;
  float2 sj = __half22float2(*(__half2*)&su);
  float2 bj = *(const float2*)&bias[li * 8 + 2 * grp];
  float o0 = fast_tanh(a0 + sj.x * d2 + bj.x);
  float o1 = fast_tanh(a1 + sj.y * d2 + bj.y);

  __half2 hv = __float22half2_rn(make_float2(o0, o1));
  *(__half2*)&Hf[(size_t)wid * 128 + li * 8 + 2 * grp] = hv;
}

// ---------------- pooling (reads fp16 Hf) ----------------

#define CH 16

__global__ __launch_bounds__(128) void pool_partial(const __half* __restrict__ Hf,
                                                    const int* __restrict__ gstart,
                                                    float* __restrict__ pmax,
                                                    float* __restrict__ psum) {
  int g = blockIdx.x, c = blockIdx.y, f = threadIdx.x;
  int s = gstart[g], e = gstart[g + 1];
  long long len = e - s;
  int cs = s + (int)(len * c / CH);
  int ce = s + (int)(len * (c + 1) / CH);
  float m = -INFINITY, sum = 0.f;
  for (int n = cs; n < ce; ++n) {
    float v = __half2float(Hf[(size_t)n * 128 + f]);
    m = fmaxf(m, v);
    sum += v;
  }
  pmax[((size_t)g * CH + c) * 128 + f] = m;
  psum[((size_t)g * CH + c) * 128 + f] = sum;
}

__global__ __launch_bounds__(128) void pool_head(const float* __restrict__ pmax,
                                                 const float* __restrict__ psum,
                                                 const int* __restrict__ gstart,
                                                 const float* __restrict__ Wout,
                                                 const float* __restrict__ bout,
                                                 float* __restrict__ out, int G) {
  __shared__ float pl[256];
  int g = blockIdx.x, f = threadIdx.x;
  float m = -INFINITY, s = 0.f;
  for (int c = 0; c < CH; ++c) {
    m = fmaxf(m, pmax[((size_t)g * CH + c) * 128 + f]);
    s += psum[((size_t)g * CH + c) * 128 + f];
  }
  int cnt = gstart[g + 1] - gstart[g];
  float mean = s / fmaxf((float)cnt, 1.0f);
  float* pooled = out + (size_t)G * 10;
  pooled[(size_t)g * 256 + f] = m;
  pooled[(size_t)g * 256 + 128 + f] = mean;
  pl[f] = m;
  pl[128 + f] = mean;
  __syncthreads();
  if (f < 10) {
    float acc = bout[f];
    for (int k = 0; k < 256; ++k) acc += pl[k] * Wout[k * 10 + f];
    out[(size_t)g * 10 + f] = acc;
  }
}

// ---------------- launch ----------------

extern "C" void kernel_launch(void* const* d_in, const int* in_sizes, int n_in,
                              void* d_out, int out_size, void* d_ws, size_t ws_size,
                              hipStream_t stream) {
  const float* x = (const float*)d_in[0];
  const int* ei = (const int*)d_in[1];
  const int* batch = (const int*)d_in[2];
  const float* W[4] = {(const float*)d_in[3], (const float*)d_in[5],
                       (const float*)d_in[7], (const float*)d_in[9]};
  const float* Bz[4] = {(const float*)d_in[4], (const float*)d_in[6],
                        (const float*)d_in[8], (const float*)d_in[10]};
  const float* Wout = (const float*)d_in[11];
  const float* bout = (const float*)d_in[12];
  const int N = in_sizes[0] / 128;
  const int E = in_sizes[1] / 2;
  const int G = 64;
  const int* srcp = ei;
  const int* dstp = ei + E;
  float* out = (float*)d_out;

  char* wsb = (char*)d_ws;
  size_t off = 0;
  auto alloc = [&](size_t bytes) -> void* {
    void* p = wsb + off;
    off = (off + bytes + 255) & ~(size_t)255;
    return p;
  };
  __half* bufA = (__half*)alloc((size_t)N * 128 * 2);  // GEMM out (fp16)
  __half* Hf = (__half*)alloc((size_t)N * 128 * 2);    // gather out (fp16)
  size_t cnt_off = off;
  int* cnt = (int*)alloc((size_t)N * 4);
  size_t cnt_span = off - cnt_off;
  int* epos = (int*)alloc((size_t)E * 4);
  float* dinv = (float*)alloc((size_t)N * 4);
  float* dinv2 = (float*)alloc((size_t)N * 4);
  int* rs = (int*)alloc((size_t)(N + 1) * 4);
  int2* edata = (int2*)alloc((size_t)E * 8);
  int* bsum = (int*)alloc(4096);
  int* boff = (int*)alloc(4096);
  int* gstart = (int*)alloc(4096);
  float* pmax = (float*)alloc((size_t)G * CH * 128 * 4);
  float* psum = (float*)alloc((size_t)G * CH * 128 * 4);
  unsigned short* Wt0Hi = (unsigned short*)alloc(16384 * 2);
  unsigned short* Wt0Lo = (unsigned short*)alloc(16384 * 2);
  unsigned short* WfHi = (unsigned short*)alloc(3 * 16384 * 2);
  unsigned short* WfLo = (unsigned short*)alloc(3 * 16384 * 2);
  if (off > ws_size) return;

  hipMemsetAsync(wsb + cnt_off, 0, cnt_span, stream);

  int nc = (E + 255) / 256;
  count_wconv<<<nc + 128, 256, 0, stream>>>(dstp, cnt, epos, E, nc, W[0], W[1],
                                            W[2], W[3], Wt0Hi, Wt0Lo, WfHi, WfLo);
  int nsb = (N + 511) / 512;
  scan_a<<<nsb, 512, 0, stream>>>(cnt, rs, bsum, dinv, dinv2, N);
  scan_b<<<1, 256, 0, stream>>>(bsum, boff, nsb, batch, gstart, N, G);
  scan_c<<<nsb, 512, 0, stream>>>(boff, rs, N, E);
  fill_k<<<(E + 255) / 256, 256, 0, stream>>>(srcp, dstp, rs, epos, dinv, edata, E);

  int ggrid = (int)(((size_t)N * 64 + 255) / 256);
  for (int l = 0; l < 4; ++l) {
    if (l == 0)
      gemm_mfma<<<(N + 127) / 128, 256, 0, stream>>>(x, Wt0Hi, Wt0Lo, bufA, N);
    else
      gemm_f16<<<(N + 127) / 128, 256, 0, stream>>>(Hf, WfHi + (l - 1) * 16384,
                                                    WfLo + (l - 1) * 16384, bufA, N);
    gather_k<<<ggrid, 256, 0, stream>>>(bufA, rs, edata, dinv2, Bz[l], Hf, N);
  }

  pool_partial<<<dim3(G, CH), 128, 0, stream>>>(Hf, gstart, pmax, psum);
  pool_head<<<G, 128, 0, stream>>>(pmax, psum, gstart, Wout, bout, out, G);
}

// Round 11
// 515.935 us; speedup vs baseline: 1.0686x; 1.0007x over previous
//
#include <hip/hip_runtime.h>
#include <hip/hip_fp16.h>
#include <cmath>

typedef __attribute__((ext_vector_type(8))) short short8;
typedef __attribute__((ext_vector_type(8))) unsigned short ushort8;
typedef __attribute__((ext_vector_type(8))) _Float16 f16x8;
typedef __attribute__((ext_vector_type(4))) float f32x4;

__device__ __forceinline__ unsigned pk_bf16(float a, float b) {
  unsigned r;
  asm("v_cvt_pk_bf16_f32 %0, %1, %2" : "=v"(r) : "v"(a), "v"(b));
  return r;  // lo16 = bf16(a), hi16 = bf16(b), RNE
}

__device__ __forceinline__ float fast_tanh(float x) {
  float e2 = __expf(2.0f * x);
  return 1.0f - 2.0f * __builtin_amdgcn_rcpf(e2 + 1.0f);
}

// f32 acc += (f16 lo/hi half of u32) * w  -- single VOP3P instruction
#define FM_LO(A, U, W) \
  asm("v_fma_mix_f32 %0, %1, %2, %0 op_sel_hi:[1,0,0]" : "+v"(A) : "v"(U), "v"(W))
#define FM_HI(A, U, W) \
  asm("v_fma_mix_f32 %0, %1, %2, %0 op_sel:[1,0,0] op_sel_hi:[1,0,0]" : "+v"(A) : "v"(U), "v"(W))

// ---------------- W0 -> transposed split-bf16 (runs before mega_a) --------

__global__ __launch_bounds__(256) void wconv0(const float* __restrict__ W0,
                                              unsigned short* __restrict__ Wt0Hi,
                                              unsigned short* __restrict__ Wt0Lo) {
  int idx = blockIdx.x * 256 + threadIdx.x;
  if (idx >= 8192) return;
  int n = idx & 127, k = (idx >> 7) * 2;
  float w0 = W0[k * 128 + n], w1 = W0[(k + 1) * 128 + n];
  unsigned h01 = pk_bf16(w0, w1);
  float hf0 = __uint_as_float(h01 << 16);
  float hf1 = __uint_as_float(h01 & 0xFFFF0000u);
  unsigned l01 = pk_bf16(w0 - hf0, w1 - hf1);
  *(unsigned*)&Wt0Hi[n * 128 + k] = h01;
  *(unsigned*)&Wt0Lo[n * 128 + k] = l01;
}

// ---------------- layer-0 GEMM block (no LDS; W from L1/L2) ----------------

__device__ __forceinline__ void gemm0_block(int bx, const float* __restrict__ A,
                                            const unsigned short* __restrict__ WtHi,
                                            const unsigned short* __restrict__ WtLo,
                                            __half* __restrict__ O, int M) {
  int tid = threadIdx.x;
  int wv = tid >> 6, lane = tid & 63;
  int r0 = bx * 128 + wv * 32;
  int lrow = lane & 15, lk = (lane >> 4) * 8;

  f32x4 acc[2][8] = {};
#pragma unroll
  for (int kk = 0; kk < 4; ++kk) {
    int k0 = kk * 32 + lk;
    short8 ahi[2], alo[2];
#pragma unroll
    for (int fr = 0; fr < 2; ++fr) {
      int row = r0 + fr * 16 + lrow;
      row = row < M ? row : M - 1;
      const float* ap = &A[(size_t)row * 128 + k0];
      float4 a0 = *(const float4*)ap;
      float4 a1 = *(const float4*)(ap + 4);
      union { short8 v; unsigned u32[4]; } h_, l_;
#define SPLIT2(slot, x, y)                              \
      {                                                 \
        unsigned hh = pk_bf16((x), (y));                \
        h_.u32[slot] = hh;                              \
        float hf0 = __uint_as_float(hh << 16);          \
        float hf1 = __uint_as_float(hh & 0xFFFF0000u);  \
        l_.u32[slot] = pk_bf16((x) - hf0, (y) - hf1);   \
      }
      SPLIT2(0, a0.x, a0.y)
      SPLIT2(1, a0.z, a0.w)
      SPLIT2(2, a1.x, a1.y)
      SPLIT2(3, a1.z, a1.w)
#undef SPLIT2
      ahi[fr] = h_.v;
      alo[fr] = l_.v;
    }
#pragma unroll
    for (int c = 0; c < 8; ++c) {
      int bidx = (c * 16 + lrow) * 128 + k0;
      short8 bhi = *(const short8*)&WtHi[bidx];
      short8 blo = *(const short8*)&WtLo[bidx];
#pragma unroll
      for (int fr = 0; fr < 2; ++fr) {
        acc[fr][c] = __builtin_amdgcn_mfma_f32_16x16x32_bf16(ahi[fr], bhi, acc[fr][c], 0, 0, 0);
        acc[fr][c] = __builtin_amdgcn_mfma_f32_16x16x32_bf16(ahi[fr], blo, acc[fr][c], 0, 0, 0);
        acc[fr][c] = __builtin_amdgcn_mfma_f32_16x16x32_bf16(alo[fr], bhi, acc[fr][c], 0, 0, 0);
      }
    }
  }
#pragma unroll
  for (int fr = 0; fr < 2; ++fr) {
#pragma unroll
    for (int c = 0; c < 8; ++c) {
#pragma unroll
      for (int r = 0; r < 4; ++r) {
        int row = r0 + fr * 16 + (lane >> 4) * 4 + r;
        if (row < M)
          O[(size_t)row * 128 + c * 16 + (lane & 15)] = __float2half(acc[fr][c][r]);
      }
    }
  }
}

// ---------------- mega kernel A: count + wconv(1-3) + gemm0, interleaved ----

__global__ __launch_bounds__(256) void mega_a(
    const int* __restrict__ dst, int* __restrict__ cnt, int* __restrict__ epos,
    int E, int ncnt, int ngemm, int p,
    const float* __restrict__ W1, const float* __restrict__ W2,
    const float* __restrict__ W3, unsigned short* __restrict__ WfHi,
    unsigned short* __restrict__ WfLo,
    const float* __restrict__ x, const unsigned short* __restrict__ Wt0Hi,
    const unsigned short* __restrict__ Wt0Lo, __half* __restrict__ bufA, int M) {
  int bid = blockIdx.x;
  int g = bid / p;
  if ((bid % p) == 0 && g < ngemm) {
    gemm0_block(g, x, Wt0Hi, Wt0Lo, bufA, M);
    return;
  }
  int before = (g < ngemm) ? (g + 1) : ngemm;  // gemm blocks with index < bid
  int other = bid - before;
  if (other < ncnt) {
    int e = other * 256 + threadIdx.x;
    if (e < E) epos[e] = atomicAdd(&cnt[dst[e]], 1);
    return;
  }
  int t = (other - ncnt) * 256 + threadIdx.x;  // 0..24575
  int l = 1 + (t >> 13);
  int idx = t & 8191;
  const float* W = (l == 1) ? W1 : (l == 2) ? W2 : W3;
  int n = idx & 127, k = (idx >> 7) * 2;
  float w0 = W[k * 128 + n], w1 = W[(k + 1) * 128 + n];
  __half2 hh = __float22half2_rn(make_float2(w0, w1));
  float r0 = __low2float(hh), r1 = __high2float(hh);
  __half2 ll = __float22half2_rn(make_float2((w0 - r0) * 1024.0f,
                                             (w1 - r1) * 1024.0f));
  *(__half2*)&WfHi[(l - 1) * 16384 + n * 128 + k] = hh;
  *(__half2*)&WfLo[(l - 1) * 16384 + n * 128 + k] = ll;
}

// ---------------- 3-phase scan ----------------

__global__ __launch_bounds__(512) void scan_a(const int* __restrict__ cnt,
                                              int* __restrict__ rs,
                                              int* __restrict__ bsum,
                                              float* __restrict__ dinv,
                                              float* __restrict__ dinv2, int n) {
  __shared__ int s[512];
  int tid = threadIdx.x;
  int gid = blockIdx.x * 512 + tid;
  int v = (gid < n) ? cnt[gid] : 0;
  if (gid < n) {
    float deg = 1.0f + (float)v;
    dinv[gid] = rsqrtf(deg);
    dinv2[gid] = __builtin_amdgcn_rcpf(deg);
  }
  s[tid] = v;
  __syncthreads();
  for (int off = 1; off < 512; off <<= 1) {
    int t = (tid >= off) ? s[tid - off] : 0;
    __syncthreads();
    s[tid] += t;
    __syncthreads();
  }
  if (gid < n) rs[gid] = s[tid] - v;
  if (tid == 511) bsum[blockIdx.x] = s[511];
}

__global__ __launch_bounds__(256) void scan_b(const int* __restrict__ bsum,
                                              int* __restrict__ boff, int nb,
                                              const int* __restrict__ batch,
                                              int* __restrict__ gstart, int n,
                                              int G) {
  __shared__ int s[256];
  int tid = threadIdx.x;
  int v = (tid < nb) ? bsum[tid] : 0;
  s[tid] = v;
  __syncthreads();
  for (int off = 1; off < 256; off <<= 1) {
    int t = (tid >= off) ? s[tid - off] : 0;
    __syncthreads();
    s[tid] += t;
    __syncthreads();
  }
  if (tid < nb) boff[tid] = s[tid] - v;
  if (tid <= G) {
    int lo = 0, hi = n;
    while (lo < hi) {
      int mid = (lo + hi) >> 1;
      if (batch[mid] < tid) lo = mid + 1;
      else hi = mid;
    }
    gstart[tid] = lo;
  }
}

__global__ __launch_bounds__(512) void scan_c(const int* __restrict__ boff,
                                              int* __restrict__ rs, int n, int E) {
  int gid = blockIdx.x * 512 + threadIdx.x;
  if (gid < n) rs[gid] += boff[blockIdx.x];
  if (gid == 0) rs[n] = E;
}

// ---------------- fill (packed edata) ----------------

__global__ __launch_bounds__(256) void fill_k(const int* __restrict__ src,
                                              const int* __restrict__ dst,
                                              const int* __restrict__ rs,
                                              const int* __restrict__ epos,
                                              const float* __restrict__ dinv,
                                              int2* __restrict__ edata, int E) {
  int e = blockIdx.x * 256 + threadIdx.x;
  if (e >= E) return;
  int s = src[e], d = dst[e];
  int pos = rs[d] + epos[e];
  int2 ed;
  ed.x = s;
  ed.y = __float_as_int(dinv[s] * dinv[d]);
  edata[pos] = ed;
}

// ---------------- layers 1-3 GEMM: fp16 A, W = Whi + Wlo*2^-10 ----------------

#define LDK 136

__global__ __launch_bounds__(256) void gemm_f16(const __half* __restrict__ Hf,
                                                const unsigned short* __restrict__ Whi,
                                                const unsigned short* __restrict__ Wlo,
                                                __half* __restrict__ O, int M) {
  __shared__ unsigned short sHi[128 * LDK];
  __shared__ unsigned short sLo[128 * LDK];
  int tid = threadIdx.x;
#pragma unroll
  for (int i = 0; i < 8; ++i) {
    int c = tid + i * 256;
    int n = c >> 4;
    int off = (c & 15) * 8;
    *(ushort8*)&sHi[n * LDK + off] = *(const ushort8*)&Whi[c * 8];
    *(ushort8*)&sLo[n * LDK + off] = *(const ushort8*)&Wlo[c * 8];
  }
  __syncthreads();

  int wv = tid >> 6, lane = tid & 63;
  int r0 = blockIdx.x * 128 + wv * 32;
  int lrow = lane & 15, lk = (lane >> 4) * 8;

  f32x4 acc[2][8] = {};
  f32x4 accL[2][8] = {};
#pragma unroll
  for (int kk = 0; kk < 4; ++kk) {
    int k0 = kk * 32 + lk;
    f16x8 a[2];
#pragma unroll
    for (int fr = 0; fr < 2; ++fr) {
      int row = r0 + fr * 16 + lrow;
      row = row < M ? row : M - 1;
      a[fr] = *(const f16x8*)&Hf[(size_t)row * 128 + k0];
    }
#pragma unroll
    for (int c = 0; c < 8; ++c) {
      int bidx = (c * 16 + lrow) * LDK + k0;
      f16x8 bhi = *(const f16x8*)&sHi[bidx];
      f16x8 blo = *(const f16x8*)&sLo[bidx];
#pragma unroll
      for (int fr = 0; fr < 2; ++fr) {
        acc[fr][c] = __builtin_amdgcn_mfma_f32_16x16x32_f16(a[fr], bhi, acc[fr][c], 0, 0, 0);
        accL[fr][c] = __builtin_amdgcn_mfma_f32_16x16x32_f16(a[fr], blo, accL[fr][c], 0, 0, 0);
      }
    }
  }
  const float ls = 1.0f / 1024.0f;
#pragma unroll
  for (int fr = 0; fr < 2; ++fr) {
#pragma unroll
    for (int c = 0; c < 8; ++c) {
#pragma unroll
      for (int r = 0; r < 4; ++r) {
        int row = r0 + fr * 16 + (lane >> 4) * 4 + r;
        if (row < M)
          O[(size_t)row * 128 + c * 16 + (lane & 15)] =
              __float2half(acc[fr][c][r] + accL[fr][c][r] * ls);
      }
    }
  }
}

// ---------------- fused gather + self-loop + bias + tanh ----------------

__global__ __launch_bounds__(256) void gather_k(const __half* __restrict__ h,
                                                const int* __restrict__ rs,
                                                const int2* __restrict__ edata,
                                                const float* __restrict__ dinv2,
                                                const float* __restrict__ bias,
                                                __half* __restrict__ Hf, int N) {
  int wid = (int)((blockIdx.x * (size_t)blockDim.x + threadIdx.x) >> 6);
  if (wid >= N) return;
  int lane = threadIdx.x & 63;
  int grp = lane >> 4;   // 0..3: edge slot
  int li = lane & 15;    // feature chunk: features [li*8, li*8+8)
  int s = rs[wid], e = rs[wid + 1];
  const uint4* hrow = (const uint4*)h;  // row i = hrow[i*16 + li]
  const unsigned long long* ed64 = (const unsigned long long*)edata;

  float ac[8] = {};
  int niter = (e - s + 15) >> 4;
  int base = s + grp;
#define ACC(U, W)                                        \
  {                                                      \
    FM_LO(ac[0], (U).x, (W)); FM_HI(ac[1], (U).x, (W));  \
    FM_LO(ac[2], (U).y, (W)); FM_HI(ac[3], (U).y, (W));  \
    FM_LO(ac[4], (U).z, (W)); FM_HI(ac[5], (U).z, (W));  \
    FM_LO(ac[6], (U).w, (W)); FM_HI(ac[7], (U).w, (W));  \
  }
  for (int it = 0; it < niter; ++it, base += 16) {
    int p0 = base, p1 = base + 4, p2 = base + 8, p3 = base + 12;
    int c0 = p0 < e ? p0 : s, c1 = p1 < e ? p1 : s;
    int c2 = p2 < e ? p2 : s, c3 = p3 < e ? p3 : s;
    unsigned long long u0 = __builtin_nontemporal_load(&ed64[c0]);
    unsigned long long u1 = __builtin_nontemporal_load(&ed64[c1]);
    unsigned long long u2 = __builtin_nontemporal_load(&ed64[c2]);
    unsigned long long u3 = __builtin_nontemporal_load(&ed64[c3]);
    unsigned i0 = (unsigned)u0, i1 = (unsigned)u1;
    unsigned i2 = (unsigned)u2, i3 = (unsigned)u3;
    float w0 = p0 < e ? __uint_as_float((unsigned)(u0 >> 32)) : 0.0f;
    float w1 = p1 < e ? __uint_as_float((unsigned)(u1 >> 32)) : 0.0f;
    float w2 = p2 < e ? __uint_as_float((unsigned)(u2 >> 32)) : 0.0f;
    float w3 = p3 < e ? __uint_as_float((unsigned)(u3 >> 32)) : 0.0f;
    uint4 v0 = hrow[(size_t)i0 * 16 + li];
    uint4 v1 = hrow[(size_t)i1 * 16 + li];
    uint4 v2 = hrow[(size_t)i2 * 16 + li];
    uint4 v3 = hrow[(size_t)i3 * 16 + li];
    ACC(v0, w0) ACC(v1, w1) ACC(v2, w2) ACC(v3, w3)
  }
#undef ACC
#pragma unroll
  for (int j = 0; j < 8; ++j) {
    ac[j] += __shfl_xor(ac[j], 16);
    ac[j] += __shfl_xor(ac[j], 32);
  }

  float a0 = grp == 0 ? ac[0] : grp == 1 ? ac[2] : grp == 2 ? ac[4] : ac[6];
  float a1 = grp == 0 ? ac[1] : grp == 1 ? ac[3] : grp == 2 ? ac[5] : ac[7];

  float d2 = dinv2[wid];
  uint4 sv = hrow[(size_t)wid * 16 + li];
  unsigned su = grp == 0 ? sv.x : grp == 1 ? sv.y : grp == 2 ? sv.z : sv.w;
  float2 sj = __half22float2(*(__half2*)&su);
  float2 bj = *(const float2*)&bias[li * 8 + 2 * grp];
  float o0 = fast_tanh(a0 + sj.x * d2 + bj.x);
  float o1 = fast_tanh(a1 + sj.y * d2 + bj.y);

  __half2 hv = __float22half2_rn(make_float2(o0, o1));
  *(__half2*)&Hf[(size_t)wid * 128 + li * 8 + 2 * grp] = hv;
}

// ---------------- pooling (reads fp16 Hf) ----------------

#define CH 16

__global__ __launch_bounds__(128) void pool_partial(const __half* __restrict__ Hf,
                                                    const int* __restrict__ gstart,
                                                    float* __restrict__ pmax,
                                                    float* __restrict__ psum) {
  int g = blockIdx.x, c = blockIdx.y, f = threadIdx.x;
  int s = gstart[g], e = gstart[g + 1];
  long long len = e - s;
  int cs = s + (int)(len * c / CH);
  int ce = s + (int)(len * (c + 1) / CH);
  float m = -INFINITY, sum = 0.f;
  for (int n = cs; n < ce; ++n) {
    float v = __half2float(Hf[(size_t)n * 128 + f]);
    m = fmaxf(m, v);
    sum += v;
  }
  pmax[((size_t)g * CH + c) * 128 + f] = m;
  psum[((size_t)g * CH + c) * 128 + f] = sum;
}

__global__ __launch_bounds__(128) void pool_head(const float* __restrict__ pmax,
                                                 const float* __restrict__ psum,
                                                 const int* __restrict__ gstart,
                                                 const float* __restrict__ Wout,
                                                 const float* __restrict__ bout,
                                                 float* __restrict__ out, int G) {
  __shared__ float pl[256];
  int g = blockIdx.x, f = threadIdx.x;
  float m = -INFINITY, s = 0.f;
  for (int c = 0; c < CH; ++c) {
    m = fmaxf(m, pmax[((size_t)g * CH + c) * 128 + f]);
    s += psum[((size_t)g * CH + c) * 128 + f];
  }
  int cnt = gstart[g + 1] - gstart[g];
  float mean = s / fmaxf((float)cnt, 1.0f);
  float* pooled = out + (size_t)G * 10;
  pooled[(size_t)g * 256 + f] = m;
  pooled[(size_t)g * 256 + 128 + f] = mean;
  pl[f] = m;
  pl[128 + f] = mean;
  __syncthreads();
  if (f < 10) {
    float acc = bout[f];
    for (int k = 0; k < 256; ++k) acc += pl[k] * Wout[k * 10 + f];
    out[(size_t)g * 10 + f] = acc;
  }
}

// ---------------- launch ----------------

extern "C" void kernel_launch(void* const* d_in, const int* in_sizes, int n_in,
                              void* d_out, int out_size, void* d_ws, size_t ws_size,
                              hipStream_t stream) {
  const float* x = (const float*)d_in[0];
  const int* ei = (const int*)d_in[1];
  const int* batch = (const int*)d_in[2];
  const float* W[4] = {(const float*)d_in[3], (const float*)d_in[5],
                       (const float*)d_in[7], (const float*)d_in[9]};
  const float* Bz[4] = {(const float*)d_in[4], (const float*)d_in[6],
                        (const float*)d_in[8], (const float*)d_in[10]};
  const float* Wout = (const float*)d_in[11];
  const float* bout = (const float*)d_in[12];
  const int N = in_sizes[0] / 128;
  const int E = in_sizes[1] / 2;
  const int G = 64;
  const int* srcp = ei;
  const int* dstp = ei + E;
  float* out = (float*)d_out;

  char* wsb = (char*)d_ws;
  size_t off = 0;
  auto alloc = [&](size_t bytes) -> void* {
    void* p = wsb + off;
    off = (off + bytes + 255) & ~(size_t)255;
    return p;
  };
  __half* bufA = (__half*)alloc((size_t)N * 128 * 2);  // GEMM out (fp16)
  __half* Hf = (__half*)alloc((size_t)N * 128 * 2);    // gather out (fp16)
  size_t cnt_off = off;
  int* cnt = (int*)alloc((size_t)N * 4);
  size_t cnt_span = off - cnt_off;
  int* epos = (int*)alloc((size_t)E * 4);
  float* dinv = (float*)alloc((size_t)N * 4);
  float* dinv2 = (float*)alloc((size_t)N * 4);
  int* rs = (int*)alloc((size_t)(N + 1) * 4);
  int2* edata = (int2*)alloc((size_t)E * 8);
  int* bsum = (int*)alloc(4096);
  int* boff = (int*)alloc(4096);
  int* gstart = (int*)alloc(4096);
  float* pmax = (float*)alloc((size_t)G * CH * 128 * 4);
  float* psum = (float*)alloc((size_t)G * CH * 128 * 4);
  unsigned short* Wt0Hi = (unsigned short*)alloc(16384 * 2);
  unsigned short* Wt0Lo = (unsigned short*)alloc(16384 * 2);
  unsigned short* WfHi = (unsigned short*)alloc(3 * 16384 * 2);
  unsigned short* WfLo = (unsigned short*)alloc(3 * 16384 * 2);
  if (off > ws_size) return;

  hipMemsetAsync(wsb + cnt_off, 0, cnt_span, stream);

  wconv0<<<32, 256, 0, stream>>>(W[0], Wt0Hi, Wt0Lo);

  int ncnt = (E + 255) / 256;
  int ngemm = (N + 127) / 128;
  int total = ncnt + 96 + ngemm;
  int p = total / ngemm;  // interleave period (>=1)
  mega_a<<<total, 256, 0, stream>>>(dstp, cnt, epos, E, ncnt, ngemm, p, W[1],
                                    W[2], W[3], WfHi, WfLo, x, Wt0Hi, Wt0Lo,
                                    bufA, N);

  int nsb = (N + 511) / 512;
  scan_a<<<nsb, 512, 0, stream>>>(cnt, rs, bsum, dinv, dinv2, N);
  scan_b<<<1, 256, 0, stream>>>(bsum, boff, nsb, batch, gstart, N, G);
  scan_c<<<nsb, 512, 0, stream>>>(boff, rs, N, E);
  fill_k<<<(E + 255) / 256, 256, 0, stream>>>(srcp, dstp, rs, epos, dinv, edata, E);

  int ggrid = (int)(((size_t)N * 64 + 255) / 256);
  for (int l = 0; l < 4; ++l) {
    if (l > 0)
      gemm_f16<<<(N + 127) / 128, 256, 0, stream>>>(Hf, WfHi + (l - 1) * 16384,
                                                    WfLo + (l - 1) * 16384, bufA, N);
    gather_k<<<ggrid, 256, 0, stream>>>(bufA, rs, edata, dinv2, Bz[l], Hf, N);
  }

  pool_partial<<<dim3(G, CH), 128, 0, stream>>>(Hf, gstart, pmax, psum);
  pool_head<<<G, 128, 0, stream>>>(pmax, psum, gstart, Wout, bout, out, G);
}